// Round 6
// baseline (312.689 us; speedup 1.0000x reference)
//
#include <hip/hip_runtime.h>

// KanLinear: out[b,o] = silu(x)@scale_base + bases@(spline_w*scale_spline)
// Round 15: B-operand direct-to-register (bypass LDS).
//  - r9..r14: five schedule variants all pinned at ~100us / MfmaUtil 35%.
//    Accounting: per CU-step MFMA=1100cyc but LDS traffic (64KB write +
//    128KB read, 2x read-dup per operand) = ~1500cyc at 128B/cyc -> LDS
//    bandwidth is the floor, not the schedule. Schedule work was futile.
//  - Fix: B comes straight from global (wbt8 8.4MB / sbT 2MB = L3-resident)
//    into VGPR fragments, register-double-buffered, loaded one step ahead.
//    Removes B's LDS write+read (96KB of 192KB per CU-step) -> LDS ~750cyc
//    < MFMA 1100cyc -> MFMA-bound. A keeps gl2lds (67MB, must not re-read).
//  - Loop stays r14 single-barrier: stage A(t+1)+load B(t+1) -> ds_read A
//    interleaved 1:4 with MFMA -> vmcnt(0)+barrier. 128^2, 2 blk/CU.
//  - kan_mix + fallback untouched.

#define BATCH 8192
#define IN_F  1024
#define OUT_F 1024
#define GRID_N 8
#define K2    (IN_F * GRID_N)          // spline K = 8192
#define KTOT  (IN_F + K2)              // 9216 (fallback path)

#define BM 128
#define BN 128
#define BK 64        // bf16 k-tile (elements)
#define BK8 128      // fp8 k-tile (bytes)

typedef __bf16 bf16x8 __attribute__((ext_vector_type(8)));
typedef float  f32x4  __attribute__((ext_vector_type(4)));
typedef int    int32x8 __attribute__((ext_vector_type(8)));

union frag { int32x8 v; uint4 q[2]; };

__device__ __forceinline__ void gl2lds16(const void* g, void* l) {
  __builtin_amdgcn_global_load_lds(
      (const __attribute__((address_space(1))) void*)g,
      (__attribute__((address_space(3))) void*)l, 16, 0, 0);
}

__device__ __forceinline__ void pack_fp8x8(const float* v, int& w0, int& w1) {
  w0 = 0; w1 = 0;
  w0 = __builtin_amdgcn_cvt_pk_fp8_f32(v[0], v[1], w0, false);
  w0 = __builtin_amdgcn_cvt_pk_fp8_f32(v[2], v[3], w0, true);
  w1 = __builtin_amdgcn_cvt_pk_fp8_f32(v[4], v[5], w1, false);
  w1 = __builtin_amdgcn_cvt_pk_fp8_f32(v[6], v[7], w1, true);
}

// ---------- launch 1: pure elementwise prep, all streams coalesced ----------
__global__ __launch_bounds__(256)
void kan_mix(const float* __restrict__ x, const float* __restrict__ sb,
             const float* __restrict__ sw, const float* __restrict__ ss,
             const float* __restrict__ grid, const float* __restrict__ sigma,
             __bf16* __restrict__ sbT, unsigned char* __restrict__ wbt8,
             unsigned char* __restrict__ Ab8, __bf16* __restrict__ sbA) {
  const int t = threadIdx.x;
  const int bx = blockIdx.x;
  if (bx < 256) {
    __shared__ float tile[64][65];
    const int o0 = (bx & 15) * 64, k0 = (bx >> 4) * 64;
    const int r = t >> 4, c4 = (t & 15) * 4;
    #pragma unroll
    for (int it = 0; it < 4; ++it) {
      const int k = k0 + r + it * 16;
      float4 v = *(const float4*)(sb + (size_t)k * OUT_F + o0 + c4);
      tile[r + it * 16][c4 + 0] = v.x; tile[r + it * 16][c4 + 1] = v.y;
      tile[r + it * 16][c4 + 2] = v.z; tile[r + it * 16][c4 + 3] = v.w;
    }
    __syncthreads();
    #pragma unroll
    for (int it = 0; it < 4; ++it) {
      const int ol = r + it * 16;
      union { __bf16 h[4]; uint2 q; } s;
      #pragma unroll
      for (int e = 0; e < 4; ++e) s.h[e] = (__bf16)tile[c4 + e][ol];
      *(uint2*)(sbT + (size_t)(o0 + ol) * IN_F + k0 + c4) = s.q;
    }
  } else if (bx < 512) {
    __shared__ float tile[64][65];        // tile[i_local][o_local]
    const int sp = bx - 256;
    const int o0 = (sp >> 4) * 64;
    const int j0 = (sp & 15) * 512;
    const int i0 = j0 >> 3;
    const int r = t >> 4, c4 = (t & 15) * 4;
    #pragma unroll
    for (int it = 0; it < 4; ++it) {
      const int i = i0 + r + it * 16;
      float4 v = *(const float4*)(ss + (size_t)i * OUT_F + o0 + c4);
      tile[r + it * 16][c4 + 0] = v.x; tile[r + it * 16][c4 + 1] = v.y;
      tile[r + it * 16][c4 + 2] = v.z; tile[r + it * 16][c4 + 3] = v.w;
    }
    __syncthreads();
    #pragma unroll
    for (int p = 0; p < 16; ++p) {
      const int f = p * 256 + t;
      const int o_l = f >> 6, i_l = f & 63;
      const float sc = tile[i_l][o_l];
      const float* swp = sw + (size_t)(o0 + o_l) * K2 + j0 + i_l * 8;
      float4 a = *(const float4*)swp;
      float4 b = *(const float4*)(swp + 4);
      float vv[8] = {a.x * sc, a.y * sc, a.z * sc, a.w * sc,
                     b.x * sc, b.y * sc, b.z * sc, b.w * sc};
      int w0, w1; pack_fp8x8(vv, w0, w1);
      *(int2*)(wbt8 + (size_t)(o0 + o_l) * K2 + j0 + i_l * 8) = make_int2(w0, w1);
    }
  } else {
    const int b = bx - 512;
    const float inv_sigma = 1.0f / sigma[0];
    const float* xrow = x + (size_t)b * IN_F;
    unsigned char* arow = Ab8 + (size_t)b * K2;
    __bf16* srow = sbA + (size_t)b * IN_F;
    {
      float4 v = ((const float4*)xrow)[t];
      float vv[4] = {v.x, v.y, v.z, v.w};
      union { __bf16 h[4]; uint2 q; } s;
      #pragma unroll
      for (int e = 0; e < 4; ++e) s.h[e] = (__bf16)(vv[e] / (1.0f + __expf(-vv[e])));
      ((uint2*)srow)[t] = s.q;
    }
    #pragma unroll
    for (int it = 0; it < 4; ++it) {
      const int i = t + it * 256;
      const float u = xrow[i];
      float4 g0 = *(const float4*)(grid + (size_t)i * GRID_N);
      float4 g1 = *(const float4*)(grid + (size_t)i * GRID_N + 4);
      float gg[8] = {g0.x, g0.y, g0.z, g0.w, g1.x, g1.y, g1.z, g1.w};
      float bb[8];
      #pragma unroll
      for (int g = 0; g < GRID_N; ++g) {
        float d = (u - gg[g]) * inv_sigma;
        bb[g] = __expf(-d * d);
      }
      int w0, w1; pack_fp8x8(bb, w0, w1);
      *(int2*)(arow + (size_t)i * GRID_N) = make_int2(w0, w1);
    }
  }
}

// ---------- launch 2: unified GEMM; A via LDS, B direct-to-reg ----------
// fp8 MX phase (K=8192, 64 steps) + bf16 phase (K=1024, 16 steps), shared acc.
__global__ __launch_bounds__(256, 2)
void kan_gemm_all(const unsigned char* __restrict__ Ab8,
                  const unsigned char* __restrict__ wbt8,
                  const __bf16* __restrict__ sbA,
                  const __bf16* __restrict__ sbT,
                  float* __restrict__ out) {
  __shared__ unsigned char smem[2][16384];   // A tiles only: 2 x 16KB

  const int tid = threadIdx.x;
  const int bx  = blockIdx.x;
  // r9 swizzle (proven): 8 consecutive bx spread over XCDs sharing col-panel.
  const int s   = bx >> 3;
  const int r0  = ((bx & 7) * 8 + (s >> 3)) * BM;
  const int c0  = (s & 7) * BN;

  const int lane = tid & 63, wave = tid >> 6;
  const int wm = wave & 1, wn = wave >> 1;
  const int quad = lane >> 4, l15 = lane & 15;

  // ---- A LDS read offsets (bytes), XOR-swizzled ----
  int a_off8[4][2];
  #pragma unroll
  for (int t4 = 0; t4 < 4; ++t4) {
    const int rowA = wm * 64 + t4 * 16 + l15;
    #pragma unroll
    for (int h = 0; h < 2; ++h)
      a_off8[t4][h] = rowA * BK8 + (((quad * 2 + h) ^ (rowA & 7)) * 16);
  }
  int a_off16[2][4];
  #pragma unroll
  for (int ks = 0; ks < 2; ++ks) {
    const int kc = ks * 4 + quad;
    #pragma unroll
    for (int t4 = 0; t4 < 4; ++t4) {
      const int rowA = wm * 64 + t4 * 16 + l15;
      a_off16[ks][t4] = (rowA * 8 + (kc ^ (rowA & 7))) * 16;
    }
  }

  // ---- A staging sources (global pre-swizzled) + linear LDS dests ----
  const unsigned char* aSrc8[4]; const __bf16* aSrc16[4]; int dstOff[4];
  #pragma unroll
  for (int it = 0; it < 4; ++it) {
    const int p = it * 256 + tid;
    const int row = p >> 3;
    const int kc  = (p & 7) ^ (row & 7);
    aSrc8[it]  = Ab8 + (size_t)(r0 + row) * K2 + kc * 16;
    aSrc16[it] = sbA + (size_t)(r0 + row) * IN_F + kc * 8;
    dstOff[it] = p * 16;
  }

  // ---- B direct-load base pointers (per-lane) ----
  // fp8: lane reads 32B at (c0+rowB)*K2 + kb + quad*32  (rowB = wn*64+t4*16+l15)
  const unsigned char* bDir8[4]; const __bf16* bDir16[4];
  #pragma unroll
  for (int t4 = 0; t4 < 4; ++t4) {
    const int rowB = wn * 64 + t4 * 16 + l15;
    bDir8[t4]  = wbt8 + (size_t)(c0 + rowB) * K2 + quad * 32;
    bDir16[t4] = sbT + (size_t)(c0 + rowB) * IN_F + quad * 8;
  }

  f32x4 zero; zero[0] = 0.f; zero[1] = 0.f; zero[2] = 0.f; zero[3] = 0.f;
  f32x4 acc[4][4];
  #pragma unroll
  for (int a = 0; a < 4; ++a)
    #pragma unroll
    for (int b = 0; b < 4; ++b) acc[a][b] = zero;

  frag bA[4], bB[4];               // fp8 B double-buffer (regs)
  bf16x8 b16A[2][4], b16B[2][4];   // bf16 B double-buffer (regs)

  auto loadB8 = [&](frag (&bv)[4], int kb) {
    #pragma unroll
    for (int t4 = 0; t4 < 4; ++t4) {
      bv[t4].q[0] = *(const uint4*)(bDir8[t4] + kb);
      bv[t4].q[1] = *(const uint4*)(bDir8[t4] + kb + 16);
    }
  };
  auto loadB16 = [&](bf16x8 (&bv)[2][4], int ke) {
    #pragma unroll
    for (int t4 = 0; t4 < 4; ++t4)
      #pragma unroll
      for (int ks = 0; ks < 2; ++ks)
        bv[ks][t4] = *(const bf16x8*)(bDir16[t4] + ke + ks * 32);
  };
  auto stageA8 = [&](unsigned char* buf, int kb) {
    #pragma unroll
    for (int it = 0; it < 4; ++it) gl2lds16(aSrc8[it] + kb, buf + dstOff[it]);
  };
  auto stageA16 = [&](unsigned char* buf, int ke) {
    #pragma unroll
    for (int it = 0; it < 4; ++it) gl2lds16(aSrc16[it] + ke, buf + dstOff[it]);
  };
  auto endbar = [&]() {
    asm volatile("s_waitcnt vmcnt(0)" ::: "memory");
    __builtin_amdgcn_sched_barrier(0);
    __builtin_amdgcn_s_barrier();
    asm volatile("" ::: "memory");
  };
  auto fp8_compute = [&](const unsigned char* sp, frag (&bv)[4]) {
    #pragma unroll
    for (int tm = 0; tm < 4; ++tm) {
      frag af;
      af.q[0] = *(const uint4*)(sp + a_off8[tm][0]);
      af.q[1] = *(const uint4*)(sp + a_off8[tm][1]);
      __builtin_amdgcn_s_setprio(1);
      #pragma unroll
      for (int tn = 0; tn < 4; ++tn)
        acc[tm][tn] = __builtin_amdgcn_mfma_scale_f32_16x16x128_f8f6f4(
            af.v, bv[tn].v, acc[tm][tn], 0, 0, 0, 0x7F7F7F7F, 0, 0x7F7F7F7F);
      __builtin_amdgcn_s_setprio(0);
    }
  };
  auto bf16_compute = [&](const unsigned char* sp, bf16x8 (&bv)[2][4]) {
    #pragma unroll
    for (int ks = 0; ks < 2; ++ks)
      #pragma unroll
      for (int tm = 0; tm < 4; ++tm) {
        bf16x8 af = *(const bf16x8*)(sp + a_off16[ks][tm]);
        __builtin_amdgcn_s_setprio(1);
        #pragma unroll
        for (int tn = 0; tn < 4; ++tn)
          acc[tm][tn] = __builtin_amdgcn_mfma_f32_16x16x32_bf16(
              af, bv[ks][tn], acc[tm][tn], 0, 0, 0);
        __builtin_amdgcn_s_setprio(0);
      }
  };

  // ---- prologue: B(0)->regs, A(0)->smem[0]; certify A(0) ----
  loadB8(bA, 0);
  stageA8(&smem[0][0], 0);
  asm volatile("s_waitcnt vmcnt(0)" ::: "memory");
  __builtin_amdgcn_s_barrier();
  asm volatile("" ::: "memory");

  // ---- phase 1: fp8 MX spline, 64 K-steps (unroll-by-2, static buffers) ----
  for (int tt = 0; tt < 32; ++tt) {
    { // even step t = 2*tt : compute smem[0]/bA; prefetch t+1 -> smem[1]/bB
      const int kb = (2 * tt + 1) * BK8;
      loadB8(bB, kb);
      stageA8(&smem[1][0], kb);
      fp8_compute(&smem[0][0], bA);
      endbar();
    }
    { // odd step t = 2*tt+1 : compute smem[1]/bB; prefetch t+2 (or bf16 chain)
      if (tt < 31) {
        const int kb = (2 * tt + 2) * BK8;
        loadB8(bA, kb);
        stageA8(&smem[0][0], kb);
      } else {                 // t = 63: chain to bf16 step 0
        loadB16(b16A, 0);
        stageA16(&smem[0][0], 0);
      }
      fp8_compute(&smem[1][0], bB);
      endbar();
    }
  }

  // ---- phase 2: bf16 base, 16 K-steps, same structure, same acc ----
  for (int ss = 0; ss < 8; ++ss) {
    { // even t16 = 2*ss : compute smem[0]/b16A; prefetch -> smem[1]/b16B
      const int ke = (2 * ss + 1) * BK;
      loadB16(b16B, ke);
      stageA16(&smem[1][0], ke);
      bf16_compute(&smem[0][0], b16A);
      endbar();
    }
    { // odd t16 = 2*ss+1 : compute smem[1]/b16B; prefetch t16+2 if any
      if (ss < 7) {
        const int ke = (2 * ss + 2) * BK;
        loadB16(b16A, ke);
        stageA16(&smem[0][0], ke);
      }
      bf16_compute(&smem[1][0], b16B);
      if (ss < 7) endbar();
    }
  }

  // ---- epilogue: plain store ----
  #pragma unroll
  for (int tm = 0; tm < 4; ++tm) {
    const int row = r0 + wm * 64 + tm * 16 + quad * 4;
    #pragma unroll
    for (int tn = 0; tn < 4; ++tn) {
      const int col = c0 + wn * 64 + tn * 16 + l15;
      float* op = out + (size_t)row * OUT_F + col;
      #pragma unroll
      for (int r = 0; r < 4; ++r)
        op[(size_t)r * OUT_F] = acc[tm][tn][r];
    }
  }
}

// ---------- fallback path (ws too small): full-W bf16 prep + fused gemm ----------
__global__ __launch_bounds__(256)
void kan_prep_w_full(const float* __restrict__ sb, const float* __restrict__ sw,
                     const float* __restrict__ ss, __bf16* __restrict__ wbt) {
  const int t = threadIdx.x;
  if (blockIdx.x < 256) {
    __shared__ float tile[64][65];
    const int o0 = (blockIdx.x & 15) * 64, k0 = (blockIdx.x >> 4) * 64;
    const int r = t >> 4, c4 = (t & 15) * 4;
    #pragma unroll
    for (int it = 0; it < 4; ++it) {
      const int k = k0 + r + it * 16;
      float4 v = *(const float4*)(sb + (size_t)k * OUT_F + o0 + c4);
      tile[r + it * 16][c4 + 0] = v.x; tile[r + it * 16][c4 + 1] = v.y;
      tile[r + it * 16][c4 + 2] = v.z; tile[r + it * 16][c4 + 3] = v.w;
    }
    __syncthreads();
    #pragma unroll
    for (int it = 0; it < 4; ++it) {
      const int ol = r + it * 16;
      union { __bf16 h[4]; uint2 q; } s;
      #pragma unroll
      for (int e = 0; e < 4; ++e) s.h[e] = (__bf16)tile[c4 + e][ol];
      *(uint2*)(wbt + (size_t)(o0 + ol) * KTOT + k0 + c4) = s.q;
    }
  } else {
    const size_t e = ((size_t)(blockIdx.x - 256) * 256 + t) * 8;
    const int o = (int)(e >> 13);
    const int j = (int)(e & 8191);
    const int i = j >> 3;
    const float sc = ss[(size_t)i * OUT_F + o];
    float4 a = *(const float4*)(sw + e);
    float4 b = *(const float4*)(sw + e + 4);
    float vv[8] = {a.x, a.y, a.z, a.w, b.x, b.y, b.z, b.w};
    union { __bf16 h[8]; uint4 q; } s;
    #pragma unroll
    for (int g = 0; g < 8; ++g) s.h[g] = (__bf16)(vv[g] * sc);
    *(uint4*)(wbt + (size_t)o * KTOT + IN_F + j) = s.q;
  }
}

__global__ __launch_bounds__(256, 2)
void kan_gemm_fused(const float* __restrict__ x, const __bf16* __restrict__ wbt,
                    const float* __restrict__ grid, const float* __restrict__ sigma,
                    float* __restrict__ out) {
  __shared__ __bf16 As[BM * BK];
  __shared__ __bf16 Bs[BN * BK];
  __shared__ float  gLds[IN_F * GRID_N];
  const int tid = threadIdx.x;
  const int bx  = blockIdx.x;
  const int c0  = (bx & 7) * BN;
  const int r0  = (bx >> 3) * BM;
  for (int idx = tid; idx < IN_F * GRID_N / 4; idx += 256)
    ((float4*)gLds)[idx] = ((const float4*)grid)[idx];
  const float inv_sigma = 1.0f / sigma[0];
  const int lane = tid & 63, wave = tid >> 6;
  const int wm = wave & 1, wn = wave >> 1;
  const int quad = lane >> 4, l15 = lane & 15;
  f32x4 zero; zero[0] = 0.f; zero[1] = 0.f; zero[2] = 0.f; zero[3] = 0.f;
  f32x4 acc[4][4];
  #pragma unroll
  for (int a = 0; a < 4; ++a)
    #pragma unroll
    for (int b = 0; b < 4; ++b) acc[a][b] = zero;
  const int m = tid >> 1, half = tid & 1;
  const float* xrow = x + (size_t)(r0 + m) * IN_F;
  __syncthreads();
  for (int kb = 0; kb < KTOT; kb += BK) {
    union { __bf16 h[32]; uint4 q[4]; } av;
    if (kb < IN_F) {
      const float4* xp = (const float4*)(xrow + kb + half * 32);
      #pragma unroll
      for (int j4 = 0; j4 < 8; ++j4) {
        float4 v = xp[j4];
        float vv[4] = {v.x, v.y, v.z, v.w};
        #pragma unroll
        for (int e = 0; e < 4; ++e)
          av.h[j4 * 4 + e] = (__bf16)(vv[e] / (1.0f + __expf(-vv[e])));
      }
    } else {
      const int i0 = (kb - IN_F) >> 3;
      float4 xv = *(const float4*)(xrow + i0 + half * 4);
      float xs[4] = {xv.x, xv.y, xv.z, xv.w};
      #pragma unroll
      for (int ii = 0; ii < 4; ++ii) {
        const float u = xs[ii];
        const float* gp = &gLds[(i0 + half * 4 + ii) * GRID_N];
        #pragma unroll
        for (int g = 0; g < GRID_N; ++g) {
          float d = (u - gp[g]) * inv_sigma;
          av.h[ii * 8 + g] = (__bf16)__expf(-d * d);
        }
      }
    }
    __syncthreads();
    {
      uint4* dst = (uint4*)&As[m * BK + half * 32];
      #pragma unroll
      for (int qd = 0; qd < 4; ++qd) dst[qd] = av.q[qd];
    }
    #pragma unroll
    for (int it = 0; it < 4; ++it) {
      const int idx = it * 2048 + tid * 8;
      const int n = idx >> 6, k = idx & 63;
      gl2lds16(wbt + (size_t)(c0 + n) * KTOT + kb + k, &Bs[idx]);
    }
    __syncthreads();
    #pragma unroll
    for (int ks = 0; ks < 2; ++ks) {
      bf16x8 af[4], bfv[4];
      #pragma unroll
      for (int t4 = 0; t4 < 4; ++t4)
        af[t4] = *(const bf16x8*)&As[(wm * 64 + t4 * 16 + l15) * BK + ks * 32 + quad * 8];
      #pragma unroll
      for (int t4 = 0; t4 < 4; ++t4)
        bfv[t4] = *(const bf16x8*)&Bs[(wn * 64 + t4 * 16 + l15) * BK + ks * 32 + quad * 8];
      #pragma unroll
      for (int tm = 0; tm < 4; ++tm)
        #pragma unroll
        for (int tn = 0; tn < 4; ++tn)
          acc[tm][tn] = __builtin_amdgcn_mfma_f32_16x16x32_bf16(
              af[tm], bfv[tn], acc[tm][tn], 0, 0, 0);
    }
  }
  #pragma unroll
  for (int tm = 0; tm < 4; ++tm) {
    const int row = r0 + wm * 64 + tm * 16 + quad * 4;
    #pragma unroll
    for (int tn = 0; tn < 4; ++tn) {
      const int col = c0 + wn * 64 + tn * 16 + l15;
      float* op = out + (size_t)row * OUT_F + col;
      #pragma unroll
      for (int r = 0; r < 4; ++r)
        op[(size_t)r * OUT_F] = acc[tm][tn][r];
    }
  }
}

extern "C" void kernel_launch(void* const* d_in, const int* in_sizes, int n_in,
                              void* d_out, int out_size, void* d_ws, size_t ws_size,
                              hipStream_t stream) {
  const float* x     = (const float*)d_in[0];
  const float* sb    = (const float*)d_in[1];
  const float* sw    = (const float*)d_in[2];
  const float* ss    = (const float*)d_in[3];
  const float* grid  = (const float*)d_in[4];
  const float* sigma = (const float*)d_in[5];
  float* out = (float*)d_out;

  const size_t SBT_BYTES = (size_t)OUT_F * IN_F * 2;   //   2 MB (bf16)
  const size_t WS_BYTES  = (size_t)OUT_F * K2;         //  8.4 MB (fp8)
  const size_t A_BYTES   = (size_t)BATCH * K2;         // 67.1 MB (fp8)
  const size_t SBA_BYTES = (size_t)BATCH * IN_F * 2;   // 16.8 MB (bf16)

  if (ws_size >= SBT_BYTES + WS_BYTES + A_BYTES + SBA_BYTES) {
    __bf16*        sbT  = (__bf16*)d_ws;
    unsigned char* wbt8 = (unsigned char*)d_ws + SBT_BYTES;
    unsigned char* Ab8  = (unsigned char*)d_ws + SBT_BYTES + WS_BYTES;
    __bf16*        sbA  = (__bf16*)((char*)d_ws + SBT_BYTES + WS_BYTES + A_BYTES);
    kan_mix<<<dim3(512 + BATCH), dim3(256), 0, stream>>>(
        x, sb, sw, ss, grid, sigma, sbT, wbt8, Ab8, sbA);
    kan_gemm_all<<<dim3((BATCH / BM) * (OUT_F / BN)), dim3(256), 0, stream>>>(
        Ab8, wbt8, sbA, sbT, out);
  } else {
    __bf16* wbt = (__bf16*)d_ws;   // 18.9 MB
    kan_prep_w_full<<<dim3(4352), dim3(256), 0, stream>>>(sb, sw, ss, wbt);
    kan_gemm_fused<<<dim3((BATCH / BM) * (OUT_F / BN)), dim3(256), 0, stream>>>(
        x, wbt, grid, sigma, out);
  }
}

// Round 7
// 301.823 us; speedup vs baseline: 1.0360x; 1.0360x over previous
//
#include <hip/hip_runtime.h>

// KanLinear: out[b,o] = silu(x)@scale_base + bases@(spline_w*scale_spline)
// Round 16: B direct-to-register, FIXED with fragment-tiled B layout.
//  - r15 diagnosis: B-direct halved LDS conflicts (8.4M->4.2M, concept
//    worked) but B loads were 16B-granule at 8KB lane stride -> 8x VMEM
//    transactions -> request-rate bound (VALUBusy 6.9%).
//  - Fix: kan_mix stores B fragment-TILED: per col-panel, per K-step, one
//    contiguous 16KB tile [row 0..127][128B]. GEMM B-frag read = dense 2KB
//    region, each 16B touched once = fully coalesced, L2/L1-resident.
//    Same bytes, same accumulation order -> bit-identical output.
//  - Per-CU-step budget: LDS = A only (96KB ~ 750cyc) < MFMA (1100cyc);
//    L2 ~64KB ~ 1150cyc; single-barrier loop overlaps them.
//  - A keeps proven gl2lds path; loop = r14 single-barrier, 128^2, 2blk/CU.

#define BATCH 8192
#define IN_F  1024
#define OUT_F 1024
#define GRID_N 8
#define K2    (IN_F * GRID_N)          // spline K = 8192
#define KTOT  (IN_F + K2)              // 9216 (fallback path)

#define BM 128
#define BN 128
#define BK 64        // bf16 k-tile (elements)
#define BK8 128      // fp8 k-tile (bytes)

typedef __bf16 bf16x8 __attribute__((ext_vector_type(8)));
typedef float  f32x4  __attribute__((ext_vector_type(4)));
typedef int    int32x8 __attribute__((ext_vector_type(8)));

union frag { int32x8 v; uint4 q[2]; };

__device__ __forceinline__ void gl2lds16(const void* g, void* l) {
  __builtin_amdgcn_global_load_lds(
      (const __attribute__((address_space(1))) void*)g,
      (__attribute__((address_space(3))) void*)l, 16, 0, 0);
}

__device__ __forceinline__ void pack_fp8x8(const float* v, int& w0, int& w1) {
  w0 = 0; w1 = 0;
  w0 = __builtin_amdgcn_cvt_pk_fp8_f32(v[0], v[1], w0, false);
  w0 = __builtin_amdgcn_cvt_pk_fp8_f32(v[2], v[3], w0, true);
  w1 = __builtin_amdgcn_cvt_pk_fp8_f32(v[4], v[5], w1, false);
  w1 = __builtin_amdgcn_cvt_pk_fp8_f32(v[6], v[7], w1, true);
}

// ---------- launch 1: elementwise prep; B outputs written fragment-TILED ----
// wbt8 tiled:  addr = ((o>>7)*64 + (j>>7))*16384 + (o&127)*128 + (j&127)
// sbT  tiled (bf16 elems): idx = ((o>>7)*16 + (k>>6))*8192 + (o&127)*64 + (k&63)
__global__ __launch_bounds__(256)
void kan_mix(const float* __restrict__ x, const float* __restrict__ sb,
             const float* __restrict__ sw, const float* __restrict__ ss,
             const float* __restrict__ grid, const float* __restrict__ sigma,
             __bf16* __restrict__ sbT, unsigned char* __restrict__ wbt8,
             unsigned char* __restrict__ Ab8, __bf16* __restrict__ sbA) {
  const int t = threadIdx.x;
  const int bx = blockIdx.x;
  if (bx < 256) {
    // ---- sb transpose (64x64 f32 tiles) -> tiled sbT ----
    __shared__ float tile[64][65];
    const int o0 = (bx & 15) * 64, k0 = (bx >> 4) * 64;
    const int r = t >> 4, c4 = (t & 15) * 4;
    #pragma unroll
    for (int it = 0; it < 4; ++it) {
      const int k = k0 + r + it * 16;
      float4 v = *(const float4*)(sb + (size_t)k * OUT_F + o0 + c4);
      tile[r + it * 16][c4 + 0] = v.x; tile[r + it * 16][c4 + 1] = v.y;
      tile[r + it * 16][c4 + 2] = v.z; tile[r + it * 16][c4 + 3] = v.w;
    }
    __syncthreads();
    #pragma unroll
    for (int it = 0; it < 4; ++it) {
      const int o = o0 + r + it * 16;
      union { __bf16 h[4]; uint2 q; } s;
      #pragma unroll
      for (int e = 0; e < 4; ++e) s.h[e] = (__bf16)tile[c4 + e][r + it * 16];
      const int k = k0 + c4;
      const size_t idx = (((size_t)(o >> 7) * 16 + (k >> 6)) * 128 + (o & 127)) * 64 + (k & 63);
      *(uint2*)(sbT + idx) = s.q;
    }
  } else if (bx < 512) {
    // ---- spline-pack -> tiled wbt8 ----
    __shared__ float tile[64][65];        // tile[i_local][o_local]
    const int sp = bx - 256;
    const int o0 = (sp >> 4) * 64;
    const int j0 = (sp & 15) * 512;
    const int i0 = j0 >> 3;
    const int r = t >> 4, c4 = (t & 15) * 4;
    #pragma unroll
    for (int it = 0; it < 4; ++it) {
      const int i = i0 + r + it * 16;
      float4 v = *(const float4*)(ss + (size_t)i * OUT_F + o0 + c4);
      tile[r + it * 16][c4 + 0] = v.x; tile[r + it * 16][c4 + 1] = v.y;
      tile[r + it * 16][c4 + 2] = v.z; tile[r + it * 16][c4 + 3] = v.w;
    }
    __syncthreads();
    #pragma unroll
    for (int p = 0; p < 16; ++p) {
      const int f = p * 256 + t;
      const int o_l = f >> 6, i_l = f & 63;
      const float sc = tile[i_l][o_l];
      const float* swp = sw + (size_t)(o0 + o_l) * K2 + j0 + i_l * 8;
      float4 a = *(const float4*)swp;
      float4 b = *(const float4*)(swp + 4);
      float vv[8] = {a.x * sc, a.y * sc, a.z * sc, a.w * sc,
                     b.x * sc, b.y * sc, b.z * sc, b.w * sc};
      int w0, w1; pack_fp8x8(vv, w0, w1);
      const int o = o0 + o_l, j = j0 + i_l * 8;
      const size_t addr = (((size_t)(o >> 7) * 64 + (j >> 7)) * 128 + (o & 127)) * 128 + (j & 127);
      *(int2*)(wbt8 + addr) = make_int2(w0, w1);
    }
  } else {
    // ---- per-row x prep: silu (bf16) + RBF bases (fp8) ----
    const int b = bx - 512;
    const float inv_sigma = 1.0f / sigma[0];
    const float* xrow = x + (size_t)b * IN_F;
    unsigned char* arow = Ab8 + (size_t)b * K2;
    __bf16* srow = sbA + (size_t)b * IN_F;
    {
      float4 v = ((const float4*)xrow)[t];
      float vv[4] = {v.x, v.y, v.z, v.w};
      union { __bf16 h[4]; uint2 q; } s;
      #pragma unroll
      for (int e = 0; e < 4; ++e) s.h[e] = (__bf16)(vv[e] / (1.0f + __expf(-vv[e])));
      ((uint2*)srow)[t] = s.q;
    }
    #pragma unroll
    for (int it = 0; it < 4; ++it) {
      const int i = t + it * 256;
      const float u = xrow[i];
      float4 g0 = *(const float4*)(grid + (size_t)i * GRID_N);
      float4 g1 = *(const float4*)(grid + (size_t)i * GRID_N + 4);
      float gg[8] = {g0.x, g0.y, g0.z, g0.w, g1.x, g1.y, g1.z, g1.w};
      float bb[8];
      #pragma unroll
      for (int g = 0; g < GRID_N; ++g) {
        float d = (u - gg[g]) * inv_sigma;
        bb[g] = __expf(-d * d);
      }
      int w0, w1; pack_fp8x8(bb, w0, w1);
      *(int2*)(arow + (size_t)i * GRID_N) = make_int2(w0, w1);
    }
  }
}

// ---------- launch 2: unified GEMM; A via LDS, B direct-from-tiled-global ----
__global__ __launch_bounds__(256, 2)
void kan_gemm_all(const unsigned char* __restrict__ Ab8,
                  const unsigned char* __restrict__ wbt8,
                  const __bf16* __restrict__ sbA,
                  const __bf16* __restrict__ sbT,
                  float* __restrict__ out) {
  __shared__ unsigned char smem[2][16384];   // A tiles only: 2 x 16KB

  const int tid = threadIdx.x;
  const int bx  = blockIdx.x;
  // r9 swizzle (proven): 8 consecutive bx spread over XCDs sharing col-panel.
  const int s   = bx >> 3;
  const int r0  = ((bx & 7) * 8 + (s >> 3)) * BM;
  const int c0  = (s & 7) * BN;
  const int panel = s & 7;                   // == c0 >> 7

  const int lane = tid & 63, wave = tid >> 6;
  const int wm = wave & 1, wn = wave >> 1;
  const int quad = lane >> 4, l15 = lane & 15;

  // ---- A LDS read offsets (bytes), XOR-swizzled ----
  int a_off8[4][2];
  #pragma unroll
  for (int t4 = 0; t4 < 4; ++t4) {
    const int rowA = wm * 64 + t4 * 16 + l15;
    #pragma unroll
    for (int h = 0; h < 2; ++h)
      a_off8[t4][h] = rowA * BK8 + (((quad * 2 + h) ^ (rowA & 7)) * 16);
  }
  int a_off16[2][4];
  #pragma unroll
  for (int ks = 0; ks < 2; ++ks) {
    const int kc = ks * 4 + quad;
    #pragma unroll
    for (int t4 = 0; t4 < 4; ++t4) {
      const int rowA = wm * 64 + t4 * 16 + l15;
      a_off16[ks][t4] = (rowA * 8 + (kc ^ (rowA & 7))) * 16;
    }
  }

  // ---- A staging sources (global pre-swizzled) + linear LDS dests ----
  const unsigned char* aSrc8[4]; const __bf16* aSrc16[4]; int dstOff[4];
  #pragma unroll
  for (int it = 0; it < 4; ++it) {
    const int p = it * 256 + tid;
    const int row = p >> 3;
    const int kc  = (p & 7) ^ (row & 7);
    aSrc8[it]  = Ab8 + (size_t)(r0 + row) * K2 + kc * 16;
    aSrc16[it] = sbA + (size_t)(r0 + row) * IN_F + kc * 8;
    dstOff[it] = p * 16;
  }

  // ---- B per-lane fragment pointers into the TILED layouts ----
  // fp8 tile t: base + t*16384; frag = rowB*128 + quad*32 (+16 for q[1])
  // bf16 tile t: base + t*8192el; frag = rowB*64 + quad*8 (+ks*32)
  const unsigned char* bFrag8[4]; const __bf16* bFrag16[4];
  #pragma unroll
  for (int t4 = 0; t4 < 4; ++t4) {
    const int rowB = wn * 64 + t4 * 16 + l15;
    bFrag8[t4]  = wbt8 + (size_t)panel * 64 * 16384 + rowB * 128 + quad * 32;
    bFrag16[t4] = sbT + (size_t)panel * 16 * 8192 + rowB * 64 + quad * 8;
  }

  f32x4 zero; zero[0] = 0.f; zero[1] = 0.f; zero[2] = 0.f; zero[3] = 0.f;
  f32x4 acc[4][4];
  #pragma unroll
  for (int a = 0; a < 4; ++a)
    #pragma unroll
    for (int b = 0; b < 4; ++b) acc[a][b] = zero;

  frag bA[4], bB[4];               // fp8 B double-buffer (regs)
  bf16x8 b16A[2][4], b16B[2][4];   // bf16 B double-buffer (regs)

  auto loadB8 = [&](frag (&bv)[4], int t) {
    #pragma unroll
    for (int t4 = 0; t4 < 4; ++t4) {
      const unsigned char* p = bFrag8[t4] + (size_t)t * 16384;
      bv[t4].q[0] = *(const uint4*)p;
      bv[t4].q[1] = *(const uint4*)(p + 16);
    }
  };
  auto loadB16 = [&](bf16x8 (&bv)[2][4], int t16) {
    #pragma unroll
    for (int t4 = 0; t4 < 4; ++t4) {
      const __bf16* p = bFrag16[t4] + (size_t)t16 * 8192;
      #pragma unroll
      for (int ks = 0; ks < 2; ++ks)
        bv[ks][t4] = *(const bf16x8*)(p + ks * 32);
    }
  };
  auto stageA8 = [&](unsigned char* buf, int kb) {
    #pragma unroll
    for (int it = 0; it < 4; ++it) gl2lds16(aSrc8[it] + kb, buf + dstOff[it]);
  };
  auto stageA16 = [&](unsigned char* buf, int ke) {
    #pragma unroll
    for (int it = 0; it < 4; ++it) gl2lds16(aSrc16[it] + ke, buf + dstOff[it]);
  };
  auto endbar = [&]() {
    asm volatile("s_waitcnt vmcnt(0)" ::: "memory");
    __builtin_amdgcn_sched_barrier(0);
    __builtin_amdgcn_s_barrier();
    asm volatile("" ::: "memory");
  };
  auto fp8_compute = [&](const unsigned char* sp, frag (&bv)[4]) {
    #pragma unroll
    for (int tm = 0; tm < 4; ++tm) {
      frag af;
      af.q[0] = *(const uint4*)(sp + a_off8[tm][0]);
      af.q[1] = *(const uint4*)(sp + a_off8[tm][1]);
      __builtin_amdgcn_s_setprio(1);
      #pragma unroll
      for (int tn = 0; tn < 4; ++tn)
        acc[tm][tn] = __builtin_amdgcn_mfma_scale_f32_16x16x128_f8f6f4(
            af.v, bv[tn].v, acc[tm][tn], 0, 0, 0, 0x7F7F7F7F, 0, 0x7F7F7F7F);
      __builtin_amdgcn_s_setprio(0);
    }
  };
  auto bf16_compute = [&](const unsigned char* sp, bf16x8 (&bv)[2][4]) {
    #pragma unroll
    for (int ks = 0; ks < 2; ++ks)
      #pragma unroll
      for (int tm = 0; tm < 4; ++tm) {
        bf16x8 af = *(const bf16x8*)(sp + a_off16[ks][tm]);
        __builtin_amdgcn_s_setprio(1);
        #pragma unroll
        for (int tn = 0; tn < 4; ++tn)
          acc[tm][tn] = __builtin_amdgcn_mfma_f32_16x16x32_bf16(
              af, bv[ks][tn], acc[tm][tn], 0, 0, 0);
        __builtin_amdgcn_s_setprio(0);
      }
  };

  // ---- prologue: B(0)->regs, A(0)->smem[0]; certify A(0) ----
  loadB8(bA, 0);
  stageA8(&smem[0][0], 0);
  asm volatile("s_waitcnt vmcnt(0)" ::: "memory");
  __builtin_amdgcn_s_barrier();
  asm volatile("" ::: "memory");

  // ---- phase 1: fp8 MX spline, 64 K-steps (unroll-by-2, static buffers) ----
  for (int tt = 0; tt < 32; ++tt) {
    { // even step t = 2*tt : compute smem[0]/bA; prefetch t+1 -> smem[1]/bB
      loadB8(bB, 2 * tt + 1);
      stageA8(&smem[1][0], (2 * tt + 1) * BK8);
      fp8_compute(&smem[0][0], bA);
      endbar();
    }
    { // odd step t = 2*tt+1 : compute smem[1]/bB; prefetch t+2 (or bf16 chain)
      if (tt < 31) {
        loadB8(bA, 2 * tt + 2);
        stageA8(&smem[0][0], (2 * tt + 2) * BK8);
      } else {                 // t = 63: chain to bf16 step 0
        loadB16(b16A, 0);
        stageA16(&smem[0][0], 0);
      }
      fp8_compute(&smem[1][0], bB);
      endbar();
    }
  }

  // ---- phase 2: bf16 base, 16 K-steps, same structure, same acc ----
  for (int ss2 = 0; ss2 < 8; ++ss2) {
    { // even t16 = 2*ss2 : compute smem[0]/b16A; prefetch -> smem[1]/b16B
      loadB16(b16B, 2 * ss2 + 1);
      stageA16(&smem[1][0], (2 * ss2 + 1) * BK);
      bf16_compute(&smem[0][0], b16A);
      endbar();
    }
    { // odd t16 = 2*ss2+1 : compute smem[1]/b16B; prefetch t16+2 if any
      if (ss2 < 7) {
        loadB16(b16A, 2 * ss2 + 2);
        stageA16(&smem[0][0], (2 * ss2 + 2) * BK);
      }
      bf16_compute(&smem[1][0], b16B);
      if (ss2 < 7) endbar();
    }
  }

  // ---- epilogue: plain store ----
  #pragma unroll
  for (int tm = 0; tm < 4; ++tm) {
    const int row = r0 + wm * 64 + tm * 16 + quad * 4;
    #pragma unroll
    for (int tn = 0; tn < 4; ++tn) {
      const int col = c0 + wn * 64 + tn * 16 + l15;
      float* op = out + (size_t)row * OUT_F + col;
      #pragma unroll
      for (int r = 0; r < 4; ++r)
        op[(size_t)r * OUT_F] = acc[tm][tn][r];
    }
  }
}

// ---------- fallback path (ws too small): full-W bf16 prep + fused gemm ----------
__global__ __launch_bounds__(256)
void kan_prep_w_full(const float* __restrict__ sb, const float* __restrict__ sw,
                     const float* __restrict__ ss, __bf16* __restrict__ wbt) {
  const int t = threadIdx.x;
  if (blockIdx.x < 256) {
    __shared__ float tile[64][65];
    const int o0 = (blockIdx.x & 15) * 64, k0 = (blockIdx.x >> 4) * 64;
    const int r = t >> 4, c4 = (t & 15) * 4;
    #pragma unroll
    for (int it = 0; it < 4; ++it) {
      const int k = k0 + r + it * 16;
      float4 v = *(const float4*)(sb + (size_t)k * OUT_F + o0 + c4);
      tile[r + it * 16][c4 + 0] = v.x; tile[r + it * 16][c4 + 1] = v.y;
      tile[r + it * 16][c4 + 2] = v.z; tile[r + it * 16][c4 + 3] = v.w;
    }
    __syncthreads();
    #pragma unroll
    for (int it = 0; it < 4; ++it) {
      const int ol = r + it * 16;
      union { __bf16 h[4]; uint2 q; } s;
      #pragma unroll
      for (int e = 0; e < 4; ++e) s.h[e] = (__bf16)tile[c4 + e][ol];
      *(uint2*)(wbt + (size_t)(o0 + ol) * KTOT + k0 + c4) = s.q;
    }
  } else {
    const size_t e = ((size_t)(blockIdx.x - 256) * 256 + t) * 8;
    const int o = (int)(e >> 13);
    const int j = (int)(e & 8191);
    const int i = j >> 3;
    const float sc = ss[(size_t)i * OUT_F + o];
    float4 a = *(const float4*)(sw + e);
    float4 b = *(const float4*)(sw + e + 4);
    float vv[8] = {a.x, a.y, a.z, a.w, b.x, b.y, b.z, b.w};
    union { __bf16 h[8]; uint4 q; } s;
    #pragma unroll
    for (int g = 0; g < 8; ++g) s.h[g] = (__bf16)(vv[g] * sc);
    *(uint4*)(wbt + (size_t)o * KTOT + IN_F + j) = s.q;
  }
}

__global__ __launch_bounds__(256, 2)
void kan_gemm_fused(const float* __restrict__ x, const __bf16* __restrict__ wbt,
                    const float* __restrict__ grid, const float* __restrict__ sigma,
                    float* __restrict__ out) {
  __shared__ __bf16 As[BM * BK];
  __shared__ __bf16 Bs[BN * BK];
  __shared__ float  gLds[IN_F * GRID_N];
  const int tid = threadIdx.x;
  const int bx  = blockIdx.x;
  const int c0  = (bx & 7) * BN;
  const int r0  = (bx >> 3) * BM;
  for (int idx = tid; idx < IN_F * GRID_N / 4; idx += 256)
    ((float4*)gLds)[idx] = ((const float4*)grid)[idx];
  const float inv_sigma = 1.0f / sigma[0];
  const int lane = tid & 63, wave = tid >> 6;
  const int wm = wave & 1, wn = wave >> 1;
  const int quad = lane >> 4, l15 = lane & 15;
  f32x4 zero; zero[0] = 0.f; zero[1] = 0.f; zero[2] = 0.f; zero[3] = 0.f;
  f32x4 acc[4][4];
  #pragma unroll
  for (int a = 0; a < 4; ++a)
    #pragma unroll
    for (int b = 0; b < 4; ++b) acc[a][b] = zero;
  const int m = tid >> 1, half = tid & 1;
  const float* xrow = x + (size_t)(r0 + m) * IN_F;
  __syncthreads();
  for (int kb = 0; kb < KTOT; kb += BK) {
    union { __bf16 h[32]; uint4 q[4]; } av;
    if (kb < IN_F) {
      const float4* xp = (const float4*)(xrow + kb + half * 32);
      #pragma unroll
      for (int j4 = 0; j4 < 8; ++j4) {
        float4 v = xp[j4];
        float vv[4] = {v.x, v.y, v.z, v.w};
        #pragma unroll
        for (int e = 0; e < 4; ++e)
          av.h[j4 * 4 + e] = (__bf16)(vv[e] / (1.0f + __expf(-vv[e])));
      }
    } else {
      const int i0 = (kb - IN_F) >> 3;
      float4 xv = *(const float4*)(xrow + i0 + half * 4);
      float xs[4] = {xv.x, xv.y, xv.z, xv.w};
      #pragma unroll
      for (int ii = 0; ii < 4; ++ii) {
        const float u = xs[ii];
        const float* gp = &gLds[(i0 + half * 4 + ii) * GRID_N];
        #pragma unroll
        for (int g = 0; g < GRID_N; ++g) {
          float d = (u - gp[g]) * inv_sigma;
          av.h[ii * 8 + g] = (__bf16)__expf(-d * d);
        }
      }
    }
    __syncthreads();
    {
      uint4* dst = (uint4*)&As[m * BK + half * 32];
      #pragma unroll
      for (int qd = 0; qd < 4; ++qd) dst[qd] = av.q[qd];
    }
    #pragma unroll
    for (int it = 0; it < 4; ++it) {
      const int idx = it * 2048 + tid * 8;
      const int n = idx >> 6, k = idx & 63;
      gl2lds16(wbt + (size_t)(c0 + n) * KTOT + kb + k, &Bs[idx]);
    }
    __syncthreads();
    #pragma unroll
    for (int ks = 0; ks < 2; ++ks) {
      bf16x8 af[4], bfv[4];
      #pragma unroll
      for (int t4 = 0; t4 < 4; ++t4)
        af[t4] = *(const bf16x8*)&As[(wm * 64 + t4 * 16 + l15) * BK + ks * 32 + quad * 8];
      #pragma unroll
      for (int t4 = 0; t4 < 4; ++t4)
        bfv[t4] = *(const bf16x8*)&Bs[(wn * 64 + t4 * 16 + l15) * BK + ks * 32 + quad * 8];
      #pragma unroll
      for (int tm = 0; tm < 4; ++tm)
        #pragma unroll
        for (int tn = 0; tn < 4; ++tn)
          acc[tm][tn] = __builtin_amdgcn_mfma_f32_16x16x32_bf16(
              af[tm], bfv[tn], acc[tm][tn], 0, 0, 0);
    }
  }
  #pragma unroll
  for (int tm = 0; tm < 4; ++tm) {
    const int row = r0 + wm * 64 + tm * 16 + quad * 4;
    #pragma unroll
    for (int tn = 0; tn < 4; ++tn) {
      const int col = c0 + wn * 64 + tn * 16 + l15;
      float* op = out + (size_t)row * OUT_F + col;
      #pragma unroll
      for (int r = 0; r < 4; ++r)
        op[(size_t)r * OUT_F] = acc[tm][tn][r];
    }
  }
}

extern "C" void kernel_launch(void* const* d_in, const int* in_sizes, int n_in,
                              void* d_out, int out_size, void* d_ws, size_t ws_size,
                              hipStream_t stream) {
  const float* x     = (const float*)d_in[0];
  const float* sb    = (const float*)d_in[1];
  const float* sw    = (const float*)d_in[2];
  const float* ss    = (const float*)d_in[3];
  const float* grid  = (const float*)d_in[4];
  const float* sigma = (const float*)d_in[5];
  float* out = (float*)d_out;

  const size_t SBT_BYTES = (size_t)OUT_F * IN_F * 2;   //   2 MB (bf16, tiled)
  const size_t WS_BYTES  = (size_t)OUT_F * K2;         //  8.4 MB (fp8, tiled)
  const size_t A_BYTES   = (size_t)BATCH * K2;         // 67.1 MB (fp8)
  const size_t SBA_BYTES = (size_t)BATCH * IN_F * 2;   // 16.8 MB (bf16)

  if (ws_size >= SBT_BYTES + WS_BYTES + A_BYTES + SBA_BYTES) {
    __bf16*        sbT  = (__bf16*)d_ws;
    unsigned char* wbt8 = (unsigned char*)d_ws + SBT_BYTES;
    unsigned char* Ab8  = (unsigned char*)d_ws + SBT_BYTES + WS_BYTES;
    __bf16*        sbA  = (__bf16*)((char*)d_ws + SBT_BYTES + WS_BYTES + A_BYTES);
    kan_mix<<<dim3(512 + BATCH), dim3(256), 0, stream>>>(
        x, sb, sw, ss, grid, sigma, sbT, wbt8, Ab8, sbA);
    kan_gemm_all<<<dim3((BATCH / BM) * (OUT_F / BN)), dim3(256), 0, stream>>>(
        Ab8, wbt8, sbA, sbT, out);
  } else {
    __bf16* wbt = (__bf16*)d_ws;   // 18.9 MB
    kan_prep_w_full<<<dim3(4352), dim3(256), 0, stream>>>(sb, sw, ss, wbt);
    kan_gemm_fused<<<dim3((BATCH / BM) * (OUT_F / BN)), dim3(256), 0, stream>>>(
        x, wbt, grid, sigma, out);
  }
}

// Round 8
// 250.904 us; speedup vs baseline: 1.2463x; 1.2029x over previous
//
#include <hip/hip_runtime.h>

// KanLinear: out[b,o] = silu(x)@scale_base + bases@(spline_w*scale_spline)
// Round 17: lock in best gemm (r12, 99.5-100.5us) + kan_mix occupancy fix.
//  - r15/r16 post-mortem: B-direct-to-reg fails unless per-INSTRUCTION lane
//    addresses are consecutive (r15: 8KB stride, r16: 128B stride -> TA
//    serializes scattered requests, VALUBusy 7-9%). Abandoned; gl2lds's
//    lane-linear addressing is the only fast staging path. Gemm reverted to
//    r12 counted-vmcnt double-buffer (best measured).
//  - kan_mix spline-pack was 256 blocks = 1/CU, 16 serial passes: a 42MB
//    stream at ~1 TB/s (occupancy-starved). Now 2048 blocks (64o x 64j
//    tiles, 2 passes) = 8x MLP. Row branch: 4 consecutive i/thread, reuses
//    the silu float4 (no re-read), 2x int4 Ab8 writes.

#define BATCH 8192
#define IN_F  1024
#define OUT_F 1024
#define GRID_N 8
#define K2    (IN_F * GRID_N)          // spline K = 8192
#define KTOT  (IN_F + K2)              // 9216 (fallback path)

#define BM 128
#define BN 128
#define BK 64        // bf16 k-tile
#define BK8 128      // fp8 k-tile (bytes)

typedef __bf16 bf16x8 __attribute__((ext_vector_type(8)));
typedef float  f32x4  __attribute__((ext_vector_type(4)));
typedef int    int32x8 __attribute__((ext_vector_type(8)));

__device__ __forceinline__ void gl2lds16(const void* g, void* l) {
  __builtin_amdgcn_global_load_lds(
      (const __attribute__((address_space(1))) void*)g,
      (__attribute__((address_space(3))) void*)l, 16, 0, 0);
}

__device__ __forceinline__ void pack_fp8x8(const float* v, int& w0, int& w1) {
  w0 = 0; w1 = 0;
  w0 = __builtin_amdgcn_cvt_pk_fp8_f32(v[0], v[1], w0, false);
  w0 = __builtin_amdgcn_cvt_pk_fp8_f32(v[2], v[3], w0, true);
  w1 = __builtin_amdgcn_cvt_pk_fp8_f32(v[4], v[5], w1, false);
  w1 = __builtin_amdgcn_cvt_pk_fp8_f32(v[6], v[7], w1, true);
}

// ---------- launch 1: elementwise prep ----------
// blocks [0,256):        sbT[o][k] = (bf16)scale_base[k][o]  (LDS transpose)
// blocks [256,2304):     spline-pack tile 64o x 64j (2048 blocks, 8x MLP)
// blocks [2304,2304+B):  row b: sbA=bf16(silu(x)), Ab8=fp8(bases)
__global__ __launch_bounds__(256)
void kan_mix(const float* __restrict__ x, const float* __restrict__ sb,
             const float* __restrict__ sw, const float* __restrict__ ss,
             const float* __restrict__ grid, const float* __restrict__ sigma,
             __bf16* __restrict__ sbT, unsigned char* __restrict__ wbt8,
             unsigned char* __restrict__ Ab8, __bf16* __restrict__ sbA) {
  const int t = threadIdx.x;
  const int bx = blockIdx.x;
  if (bx < 256) {
    // ---- sb transpose (64x64 f32 tiles) ----
    __shared__ float tile[64][65];
    const int o0 = (bx & 15) * 64, k0 = (bx >> 4) * 64;
    const int r = t >> 4, c4 = (t & 15) * 4;
    #pragma unroll
    for (int it = 0; it < 4; ++it) {
      const int k = k0 + r + it * 16;
      float4 v = *(const float4*)(sb + (size_t)k * OUT_F + o0 + c4);
      tile[r + it * 16][c4 + 0] = v.x; tile[r + it * 16][c4 + 1] = v.y;
      tile[r + it * 16][c4 + 2] = v.z; tile[r + it * 16][c4 + 3] = v.w;
    }
    __syncthreads();
    #pragma unroll
    for (int it = 0; it < 4; ++it) {
      const int ol = r + it * 16;
      union { __bf16 h[4]; uint2 q; } s;
      #pragma unroll
      for (int e = 0; e < 4; ++e) s.h[e] = (__bf16)tile[c4 + e][ol];
      *(uint2*)(sbT + (size_t)(o0 + ol) * IN_F + k0 + c4) = s.q;
    }
  } else if (bx < 2304) {
    // ---- spline-pack: tile = 64 o x 64 j (8 i), 2048 blocks ----
    __shared__ float tile[8][65];         // tile[i_local][o_local]
    const int sp = bx - 256;              // [0,2048)
    const int o0 = (sp >> 7) * 64;        // 16 o-tiles
    const int j0 = (sp & 127) * 64;       // 128 j-tiles
    const int i0 = j0 >> 3;               // 8 i's per tile
    if (t < 128) {                        // stage ss[i0..i0+8)[o0..o0+64)
      const int r = t >> 4, c4 = (t & 15) * 4;
      float4 v = *(const float4*)(ss + (size_t)(i0 + r) * OUT_F + o0 + c4);
      tile[r][c4 + 0] = v.x; tile[r][c4 + 1] = v.y;
      tile[r][c4 + 2] = v.z; tile[r][c4 + 3] = v.w;
    }
    __syncthreads();
    // 512 (o_l, i_l) pairs, i_l fastest -> sw reads & wbt8 writes coalesced
    #pragma unroll
    for (int p = 0; p < 2; ++p) {
      const int f = p * 256 + t;
      const int o_l = f >> 3, i_l = f & 7;
      const float sc = tile[i_l][o_l];
      const float* swp = sw + (size_t)(o0 + o_l) * K2 + j0 + i_l * 8;
      float4 a = *(const float4*)swp;
      float4 b = *(const float4*)(swp + 4);
      float vv[8] = {a.x * sc, a.y * sc, a.z * sc, a.w * sc,
                     b.x * sc, b.y * sc, b.z * sc, b.w * sc};
      int w0, w1; pack_fp8x8(vv, w0, w1);
      *(int2*)(wbt8 + (size_t)(o0 + o_l) * K2 + j0 + i_l * 8) = make_int2(w0, w1);
    }
  } else {
    // ---- per-row x prep: silu (bf16) + RBF bases (fp8), 4 i per thread ----
    const int b = bx - 2304;
    const float inv_sigma = 1.0f / sigma[0];
    const float* xrow = x + (size_t)b * IN_F;
    unsigned char* arow = Ab8 + (size_t)b * K2;
    __bf16* srow = sbA + (size_t)b * IN_F;
    float4 v = ((const float4*)xrow)[t];
    float xs[4] = {v.x, v.y, v.z, v.w};
    {
      union { __bf16 h[4]; uint2 q; } s;
      #pragma unroll
      for (int e = 0; e < 4; ++e) s.h[e] = (__bf16)(xs[e] / (1.0f + __expf(-xs[e])));
      ((uint2*)srow)[t] = s.q;
    }
    int w[8];
    #pragma unroll
    for (int e = 0; e < 4; ++e) {
      const int i = 4 * t + e;
      float4 g0 = *(const float4*)(grid + (size_t)i * GRID_N);
      float4 g1 = *(const float4*)(grid + (size_t)i * GRID_N + 4);
      float gg[8] = {g0.x, g0.y, g0.z, g0.w, g1.x, g1.y, g1.z, g1.w};
      float bb[8];
      #pragma unroll
      for (int g = 0; g < GRID_N; ++g) {
        float d = (xs[e] - gg[g]) * inv_sigma;
        bb[g] = __expf(-d * d);
      }
      pack_fp8x8(bb, w[2 * e], w[2 * e + 1]);
    }
    *(int4*)(arow + (size_t)t * 32)      = make_int4(w[0], w[1], w[2], w[3]);
    *(int4*)(arow + (size_t)t * 32 + 16) = make_int4(w[4], w[5], w[6], w[7]);
  }
}

// ---------- launch 2: unified GEMM, counted-vmcnt double-buffered (r12) ----
__global__ __launch_bounds__(256)
void kan_gemm_all(const unsigned char* __restrict__ Ab8,
                  const unsigned char* __restrict__ wbt8,
                  const __bf16* __restrict__ sbA,
                  const __bf16* __restrict__ sbT,
                  float* __restrict__ out) {
  // [buf][ A: 0..16K | B: 16K..32K ]; 64 KB total -> 2 blocks/CU
  __shared__ unsigned char smem[2][32768];

  const int tid = threadIdx.x;
  const int bx  = blockIdx.x;
  const int s   = bx >> 3;
  const int r0  = ((bx & 7) * 8 + (s >> 3)) * BM;
  const int c0  = (s & 7) * BN;

  const int lane = tid & 63, wave = tid >> 6;
  const int wm = wave & 1, wn = wave >> 1;
  const int quad = lane >> 4, l15 = lane & 15;

  int a_off8[4][2], b_off8[4][2];
  #pragma unroll
  for (int t4 = 0; t4 < 4; ++t4) {
    const int rowA = wm * 64 + t4 * 16 + l15;
    const int rowB = wn * 64 + t4 * 16 + l15;
    #pragma unroll
    for (int h = 0; h < 2; ++h) {
      a_off8[t4][h] = rowA * BK8 + (((quad * 2 + h) ^ (rowA & 7)) * 16);
      b_off8[t4][h] = 16384 + rowB * BK8 + (((quad * 2 + h) ^ (rowB & 7)) * 16);
    }
  }
  int a_off16[2][4], b_off16[2][4];
  #pragma unroll
  for (int ks = 0; ks < 2; ++ks) {
    const int kc = ks * 4 + quad;
    #pragma unroll
    for (int t4 = 0; t4 < 4; ++t4) {
      const int rowA = wm * 64 + t4 * 16 + l15;
      a_off16[ks][t4] = (rowA * 8 + (kc ^ (rowA & 7))) * 16;
      const int rowB = wn * 64 + t4 * 16 + l15;
      b_off16[ks][t4] = 16384 + (rowB * 8 + (kc ^ (rowB & 7))) * 16;
    }
  }

  const unsigned char* aSrc8[4]; const unsigned char* bSrc8[4];
  const __bf16* aSrc16[4]; const __bf16* bSrc16[4]; int dstOff[4];
  #pragma unroll
  for (int it = 0; it < 4; ++it) {
    const int p = it * 256 + tid;
    const int row = p >> 3;
    const int kc  = (p & 7) ^ (row & 7);
    aSrc8[it]  = Ab8  + (size_t)(r0 + row) * K2 + kc * 16;
    bSrc8[it]  = wbt8 + (size_t)(c0 + row) * K2 + kc * 16;
    aSrc16[it] = sbA  + (size_t)(r0 + row) * IN_F + kc * 8;
    bSrc16[it] = sbT  + (size_t)(c0 + row) * IN_F + kc * 8;
    dstOff[it] = p * 16;
  }

  f32x4 zero; zero[0] = 0.f; zero[1] = 0.f; zero[2] = 0.f; zero[3] = 0.f;
  f32x4 acc[4][4];
  #pragma unroll
  for (int a = 0; a < 4; ++a)
    #pragma unroll
    for (int b = 0; b < 4; ++b) acc[a][b] = zero;

  // ---- prologue: stage fp8 tile 0 into buf 0 (8 loads in flight) ----
  #pragma unroll
  for (int it = 0; it < 4; ++it) {
    gl2lds16(aSrc8[it], &smem[0][dstOff[it]]);
    gl2lds16(bSrc8[it], &smem[0][16384 + dstOff[it]]);
  }

  int cur = 0;
  // ---- phase 1: fp8 MX spline, 64 K-steps ----
  for (int t = 0; t < 64; ++t) {
    const int nxt = cur ^ 1;
    if (t < 63) {                       // prefetch next fp8 tile
      const int kb = (t + 1) * BK8;
      #pragma unroll
      for (int it = 0; it < 4; ++it) {
        gl2lds16(aSrc8[it] + kb, &smem[nxt][dstOff[it]]);
        gl2lds16(bSrc8[it] + kb, &smem[nxt][16384 + dstOff[it]]);
      }
    } else {                            // chain: first bf16 tile
      #pragma unroll
      for (int it = 0; it < 4; ++it) {
        gl2lds16(aSrc16[it], &smem[nxt][dstOff[it]]);
        gl2lds16(bSrc16[it], &smem[nxt][16384 + dstOff[it]]);
      }
    }
    // wait tile t's 8 loads only; prefetch (8 newer) stays in flight
    asm volatile("s_waitcnt vmcnt(8)" ::: "memory");
    __builtin_amdgcn_s_barrier();
    asm volatile("" ::: "memory");
    const unsigned char* sp = smem[cur];
    union frag { int32x8 v; uint4 q[2]; };
    frag af[4], bfv[4];
    #pragma unroll
    for (int t4 = 0; t4 < 4; ++t4) {
      af[t4].q[0]  = *(const uint4*)(sp + a_off8[t4][0]);
      af[t4].q[1]  = *(const uint4*)(sp + a_off8[t4][1]);
      bfv[t4].q[0] = *(const uint4*)(sp + b_off8[t4][0]);
      bfv[t4].q[1] = *(const uint4*)(sp + b_off8[t4][1]);
    }
    __builtin_amdgcn_s_setprio(1);
    #pragma unroll
    for (int tm = 0; tm < 4; ++tm)
      #pragma unroll
      for (int tn = 0; tn < 4; ++tn)
        acc[tm][tn] = __builtin_amdgcn_mfma_scale_f32_16x16x128_f8f6f4(
            af[tm].v, bfv[tn].v, acc[tm][tn],
            0, 0, 0, 0x7F7F7F7F, 0, 0x7F7F7F7F);
    __builtin_amdgcn_s_setprio(0);
    asm volatile("" ::: "memory");
    __builtin_amdgcn_s_barrier();       // all readers of cur done
    asm volatile("" ::: "memory");
    cur = nxt;
  }

  // ---- phase 2: bf16 base, 16 K-steps, same structure, same acc ----
  for (int t = 0; t < 16; ++t) {
    const int nxt = cur ^ 1;
    if (t < 15) {
      const int ke = (t + 1) * BK;      // element offset
      #pragma unroll
      for (int it = 0; it < 4; ++it) {
        gl2lds16(aSrc16[it] + ke, &smem[nxt][dstOff[it]]);
        gl2lds16(bSrc16[it] + ke, &smem[nxt][16384 + dstOff[it]]);
      }
      asm volatile("s_waitcnt vmcnt(8)" ::: "memory");
    } else {
      asm volatile("s_waitcnt vmcnt(0)" ::: "memory");
    }
    __builtin_amdgcn_s_barrier();
    asm volatile("" ::: "memory");
    const unsigned char* sp = smem[cur];
    #pragma unroll
    for (int ks = 0; ks < 2; ++ks) {
      bf16x8 af[4], bfv[4];
      #pragma unroll
      for (int t4 = 0; t4 < 4; ++t4) af[t4]  = *(const bf16x8*)(sp + a_off16[ks][t4]);
      #pragma unroll
      for (int t4 = 0; t4 < 4; ++t4) bfv[t4] = *(const bf16x8*)(sp + b_off16[ks][t4]);
      __builtin_amdgcn_s_setprio(1);
      #pragma unroll
      for (int tm = 0; tm < 4; ++tm)
        #pragma unroll
        for (int tn = 0; tn < 4; ++tn)
          acc[tm][tn] = __builtin_amdgcn_mfma_f32_16x16x32_bf16(
              af[tm], bfv[tn], acc[tm][tn], 0, 0, 0);
      __builtin_amdgcn_s_setprio(0);
    }
    asm volatile("" ::: "memory");
    __builtin_amdgcn_s_barrier();
    asm volatile("" ::: "memory");
    cur = nxt;
  }

  // ---- epilogue: plain store ----
  #pragma unroll
  for (int tm = 0; tm < 4; ++tm) {
    const int row = r0 + wm * 64 + tm * 16 + quad * 4;
    #pragma unroll
    for (int tn = 0; tn < 4; ++tn) {
      const int col = c0 + wn * 64 + tn * 16 + l15;
      float* op = out + (size_t)row * OUT_F + col;
      #pragma unroll
      for (int r = 0; r < 4; ++r)
        op[(size_t)r * OUT_F] = acc[tm][tn][r];
    }
  }
}

// ---------- fallback path (ws too small): full-W bf16 prep + fused gemm ----------
__global__ __launch_bounds__(256)
void kan_prep_w_full(const float* __restrict__ sb, const float* __restrict__ sw,
                     const float* __restrict__ ss, __bf16* __restrict__ wbt) {
  const int t = threadIdx.x;
  if (blockIdx.x < 256) {
    __shared__ float tile[64][65];
    const int o0 = (blockIdx.x & 15) * 64, k0 = (blockIdx.x >> 4) * 64;
    const int r = t >> 4, c4 = (t & 15) * 4;
    #pragma unroll
    for (int it = 0; it < 4; ++it) {
      const int k = k0 + r + it * 16;
      float4 v = *(const float4*)(sb + (size_t)k * OUT_F + o0 + c4);
      tile[r + it * 16][c4 + 0] = v.x; tile[r + it * 16][c4 + 1] = v.y;
      tile[r + it * 16][c4 + 2] = v.z; tile[r + it * 16][c4 + 3] = v.w;
    }
    __syncthreads();
    #pragma unroll
    for (int it = 0; it < 4; ++it) {
      const int ol = r + it * 16;
      union { __bf16 h[4]; uint2 q; } s;
      #pragma unroll
      for (int e = 0; e < 4; ++e) s.h[e] = (__bf16)tile[c4 + e][ol];
      *(uint2*)(wbt + (size_t)(o0 + ol) * KTOT + k0 + c4) = s.q;
    }
  } else {
    const size_t e = ((size_t)(blockIdx.x - 256) * 256 + t) * 8;
    const int o = (int)(e >> 13);
    const int j = (int)(e & 8191);
    const int i = j >> 3;
    const float sc = ss[(size_t)i * OUT_F + o];
    float4 a = *(const float4*)(sw + e);
    float4 b = *(const float4*)(sw + e + 4);
    float vv[8] = {a.x, a.y, a.z, a.w, b.x, b.y, b.z, b.w};
    union { __bf16 h[8]; uint4 q; } s;
    #pragma unroll
    for (int g = 0; g < 8; ++g) s.h[g] = (__bf16)(vv[g] * sc);
    *(uint4*)(wbt + (size_t)o * KTOT + IN_F + j) = s.q;
  }
}

__global__ __launch_bounds__(256, 2)
void kan_gemm_fused(const float* __restrict__ x, const __bf16* __restrict__ wbt,
                    const float* __restrict__ grid, const float* __restrict__ sigma,
                    float* __restrict__ out) {
  __shared__ __bf16 As[BM * BK];
  __shared__ __bf16 Bs[BN * BK];
  __shared__ float  gLds[IN_F * GRID_N];
  const int tid = threadIdx.x;
  const int bx  = blockIdx.x;
  const int c0  = (bx & 7) * BN;
  const int r0  = (bx >> 3) * BM;
  for (int idx = tid; idx < IN_F * GRID_N / 4; idx += 256)
    ((float4*)gLds)[idx] = ((const float4*)grid)[idx];
  const float inv_sigma = 1.0f / sigma[0];
  const int lane = tid & 63, wave = tid >> 6;
  const int wm = wave & 1, wn = wave >> 1;
  const int quad = lane >> 4, l15 = lane & 15;
  f32x4 zero; zero[0] = 0.f; zero[1] = 0.f; zero[2] = 0.f; zero[3] = 0.f;
  f32x4 acc[4][4];
  #pragma unroll
  for (int a = 0; a < 4; ++a)
    #pragma unroll
    for (int b = 0; b < 4; ++b) acc[a][b] = zero;
  const int m = tid >> 1, half = tid & 1;
  const float* xrow = x + (size_t)(r0 + m) * IN_F;
  __syncthreads();
  for (int kb = 0; kb < KTOT; kb += BK) {
    union { __bf16 h[32]; uint4 q[4]; } av;
    if (kb < IN_F) {
      const float4* xp = (const float4*)(xrow + kb + half * 32);
      #pragma unroll
      for (int j4 = 0; j4 < 8; ++j4) {
        float4 v = xp[j4];
        float vv[4] = {v.x, v.y, v.z, v.w};
        #pragma unroll
        for (int e = 0; e < 4; ++e)
          av.h[j4 * 4 + e] = (__bf16)(vv[e] / (1.0f + __expf(-vv[e])));
      }
    } else {
      const int i0 = (kb - IN_F) >> 3;
      float4 xv = *(const float4*)(xrow + i0 + half * 4);
      float xs[4] = {xv.x, xv.y, xv.z, xv.w};
      #pragma unroll
      for (int ii = 0; ii < 4; ++ii) {
        const float u = xs[ii];
        const float* gp = &gLds[(i0 + half * 4 + ii) * GRID_N];
        #pragma unroll
        for (int g = 0; g < GRID_N; ++g) {
          float d = (u - gp[g]) * inv_sigma;
          av.h[ii * 8 + g] = (__bf16)__expf(-d * d);
        }
      }
    }
    __syncthreads();
    {
      uint4* dst = (uint4*)&As[m * BK + half * 32];
      #pragma unroll
      for (int qd = 0; qd < 4; ++qd) dst[qd] = av.q[qd];
    }
    #pragma unroll
    for (int it = 0; it < 4; ++it) {
      const int idx = it * 2048 + tid * 8;
      const int n = idx >> 6, k = idx & 63;
      gl2lds16(wbt + (size_t)(c0 + n) * KTOT + kb + k, &Bs[idx]);
    }
    __syncthreads();
    #pragma unroll
    for (int ks = 0; ks < 2; ++ks) {
      bf16x8 af[4], bfv[4];
      #pragma unroll
      for (int t4 = 0; t4 < 4; ++t4)
        af[t4] = *(const bf16x8*)&As[(wm * 64 + t4 * 16 + l15) * BK + ks * 32 + quad * 8];
      #pragma unroll
      for (int t4 = 0; t4 < 4; ++t4)
        bfv[t4] = *(const bf16x8*)&Bs[(wn * 64 + t4 * 16 + l15) * BK + ks * 32 + quad * 8];
      #pragma unroll
      for (int tm = 0; tm < 4; ++tm)
        #pragma unroll
        for (int tn = 0; tn < 4; ++tn)
          acc[tm][tn] = __builtin_amdgcn_mfma_f32_16x16x32_bf16(
              af[tm], bfv[tn], acc[tm][tn], 0, 0, 0);
    }
  }
  #pragma unroll
  for (int tm = 0; tm < 4; ++tm) {
    const int row = r0 + wm * 64 + tm * 16 + quad * 4;
    #pragma unroll
    for (int tn = 0; tn < 4; ++tn) {
      const int col = c0 + wn * 64 + tn * 16 + l15;
      float* op = out + (size_t)row * OUT_F + col;
      #pragma unroll
      for (int r = 0; r < 4; ++r)
        op[(size_t)r * OUT_F] = acc[tm][tn][r];
    }
  }
}

extern "C" void kernel_launch(void* const* d_in, const int* in_sizes, int n_in,
                              void* d_out, int out_size, void* d_ws, size_t ws_size,
                              hipStream_t stream) {
  const float* x     = (const float*)d_in[0];
  const float* sb    = (const float*)d_in[1];
  const float* sw    = (const float*)d_in[2];
  const float* ss    = (const float*)d_in[3];
  const float* grid  = (const float*)d_in[4];
  const float* sigma = (const float*)d_in[5];
  float* out = (float*)d_out;

  const size_t SBT_BYTES = (size_t)OUT_F * IN_F * 2;   //   2 MB (bf16)
  const size_t WS_BYTES  = (size_t)OUT_F * K2;         //  8.4 MB (fp8)
  const size_t A_BYTES   = (size_t)BATCH * K2;         // 67.1 MB (fp8)
  const size_t SBA_BYTES = (size_t)BATCH * IN_F * 2;   // 16.8 MB (bf16)

  if (ws_size >= SBT_BYTES + WS_BYTES + A_BYTES + SBA_BYTES) {
    __bf16*        sbT  = (__bf16*)d_ws;
    unsigned char* wbt8 = (unsigned char*)d_ws + SBT_BYTES;
    unsigned char* Ab8  = (unsigned char*)d_ws + SBT_BYTES + WS_BYTES;
    __bf16*        sbA  = (__bf16*)((char*)d_ws + SBT_BYTES + WS_BYTES + A_BYTES);
    kan_mix<<<dim3(2304 + BATCH), dim3(256), 0, stream>>>(
        x, sb, sw, ss, grid, sigma, sbT, wbt8, Ab8, sbA);
    kan_gemm_all<<<dim3((BATCH / BM) * (OUT_F / BN)), dim3(256), 0, stream>>>(
        Ab8, wbt8, sbA, sbT, out);
  } else {
    __bf16* wbt = (__bf16*)d_ws;   // 18.9 MB
    kan_prep_w_full<<<dim3(4352), dim3(256), 0, stream>>>(sb, sw, ss, wbt);
    kan_gemm_fused<<<dim3((BATCH / BM) * (OUT_F / BN)), dim3(256), 0, stream>>>(
        x, wbt, grid, sigma, out);
  }
}